// Round 7
// baseline (1082.848 us; speedup 1.0000x reference)
//
#include <hip/hip_runtime.h>
#include <math.h>

// Problem constants
#define BB 512
#define SS 64
#define DD 128
#define FF 256   // 2D
#define NSYM 128
#define STK 16
#define NDEPTH 8

typedef _Float16 half_t;
typedef __attribute__((ext_vector_type(4))) _Float16 half4;
typedef __attribute__((ext_vector_type(8))) _Float16 half8;
typedef __attribute__((ext_vector_type(4))) float f32x4;

// Workspace offsets (in floats)
#define Z_OFF      0ull                    // B*S*F      = 8388608
#define QKV_OFF    8388608ull              // WT32 + GT/WvT split planes
#define MEM_OFF    33554432ull             // B*16*F     = 2097152
#define PTR_OFF    41943040ull             // B*16       = 8192
#define ZF1_OFF    41951232ull             // B*256      = 131072
#define ZF2_OFF    42082304ull             // B*256      = 131072
#define READ_OFF   42213376ull             // B*256      = 131072
#define PROBS_OFF  42344448ull             // B*128      = 65536
#define DELTA_OFF  42409984ull             // B*256      = 131072 (read + quant)
#define HALT_OFF   42541056ull             // B          = 512
#define PVAL_OFF   42541568ull             // B          = 512
#define WACT_OFF   42542080ull             // B          = 512
#define MAGP_OFF   42542592ull             // B*2        = 1024
#define MQKV_OFF   42740224ull             // 196608 floats (MTh+MTl fp16)
#define CB2_OFF    42936832ull             // 128

// ---------------------------------------------------------------------------
// Combined transposed weight, fp32: WT32[h][c][e] = W_h[e][c], h in {q,k,v}
__global__ void k_buildwt32(const float* __restrict__ wr, const float* __restrict__ wi,
                            float* __restrict__ WT32) {
    int idx = blockIdx.x * 256 + threadIdx.x;   // 196608 total, grid=768
    if (idx >= 768 * 256) return;
    int col = idx >> 8;     // 0..767 = h*256 + c
    int e   = idx & 255;
    int h   = col >> 8;
    int c   = col & 255;
    const float* Wr = wr + h * DD * DD;
    const float* Wi = wi + h * DD * DD;
    float v;
    if (c < DD) {
        v = (e < DD) ? Wr[c * DD + e] : -Wi[c * DD + (e - DD)];
    } else {
        int j = c - DD;
        v = (e < DD) ? Wi[j * DD + e] : Wr[j * DD + (e - DD)];
    }
    WT32[idx] = v;
}

// GT[n][e] = G[e][n] = sum_c Wq[e][c]*Wk[n][c], split to fp16 h/l (unscaled).
__global__ __launch_bounds__(256) void k_buildG(const float* __restrict__ WT32,
                                                half_t* __restrict__ GTh,
                                                half_t* __restrict__ GTl) {
    __shared__ float kcol[256];
    int n = blockIdx.x;       // 0..255
    int e = threadIdx.x;      // 0..255
    kcol[e] = WT32[65536 + e * 256 + n];   // Wk[n][c=e]
    __syncthreads();
    float s = 0.f;
    for (int c = 0; c < 256; ++c) s += kcol[c] * WT32[c * 256 + e];  // Wq[e][c]
    half_t h = (half_t)s;
    GTh[n * 256 + e] = h;
    GTl[n * 256 + e] = (half_t)(s - (float)h);
}

__global__ void k_splitWv(const float* __restrict__ WT32,
                          half_t* __restrict__ WvTh, half_t* __restrict__ WvTl) {
    int idx = blockIdx.x * 256 + threadIdx.x;   // 65536, grid 256
    float v = WT32[131072 + idx];   // WvT[n][e] = Wv[e][n]
    half_t h = (half_t)v;
    WvTh[idx] = h;
    WvTl[idx] = (half_t)(v - (float)h);
}

// Memory-path combined transposed split weights.
__global__ void k_buildwt(const float* __restrict__ wr, const float* __restrict__ wi,
                          half_t* __restrict__ WTh, half_t* __restrict__ WTl) {
    int idx = blockIdx.x * 256 + threadIdx.x;   // 196608 total, grid=768
    if (idx >= 768 * 256) return;
    int col = idx >> 8;
    int e   = idx & 255;
    int h   = col >> 8;
    int c   = col & 255;
    const float* Wr = wr + h * DD * DD;
    const float* Wi = wi + h * DD * DD;
    float v;
    if (c < DD) {
        v = (e < DD) ? Wr[c * DD + e] : -Wi[c * DD + (e - DD)];
    } else {
        int j = c - DD;
        v = (e < DD) ? Wi[j * DD + e] : Wr[j * DD + (e - DD)];
    }
    half_t hh = (half_t)v;
    WTh[idx] = hh;
    WTl[idx] = (half_t)(v - (float)hh);
}

__global__ void k_cb2(const float* __restrict__ cb, float* __restrict__ cb2) {
    int n = threadIdx.x;   // 128 threads
    float s = 0.f;
    for (int c = 0; c < FF; ++c) { float v = cb[n * FF + c]; s += v * v; }
    cb2[n] = s;
}

__global__ __launch_bounds__(256) void k_init(const float* __restrict__ zr_in,
                                              const float* __restrict__ zi_in,
                                              float* __restrict__ z, float* __restrict__ memv,
                                              float* __restrict__ ptrv, float* __restrict__ probs,
                                              float* __restrict__ halt, float* __restrict__ acc,
                                              float* __restrict__ delta, float* __restrict__ wact) {
    size_t idx = (size_t)blockIdx.x * 256 + threadIdx.x;  // grid 32768 -> 8388608
    int c = (int)(idx & 255);
    size_t bs = idx >> 8;
    z[idx] = (c < DD) ? zr_in[bs * DD + c] : zi_in[bs * DD + (c - DD)];
    acc[idx] = 0.f;
    if (idx < 2097152) memv[idx] = 0.f;
    if (idx < 131072) delta[idx] = 0.f;
    if (idx < 8192)  ptrv[idx] = ((idx & 15) == 0) ? 1.f : 0.f;
    if (idx < 65536) probs[idx] = 0.f;
    if (idx < 512)   { halt[idx] = 0.f; wact[idx] = 0.f; }
}

// ---------------------------------------------------------------------------
// Fused attention step, 8 waves (512 thr), 1 block/CU, 2 waves/SIMD. (UNCHANGED from R6)
__global__ __launch_bounds__(512, 1) void k_attn8(
        float* __restrict__ z,
        const half_t* __restrict__ GTh, const half_t* __restrict__ GTl,
        const half_t* __restrict__ WvTh, const half_t* __restrict__ WvTl,
        const float* __restrict__ delta, const float* __restrict__ wact,
        float* __restrict__ acc, float* __restrict__ zf1) {
    __shared__ half_t Zh[16896];         // 64 x 264 (stride-pad), 33 KB
    __shared__ half_t Zl[16896];         // 33 KB
    __shared__ half_t Ubuf[2][18432];    // union: T[64][264] / VT[256][72], 72 KB
    __shared__ half_t Pbuf[2][4][1152];  // P split, owner-wave x [16 q][72 j], 18 KB

    int b = blockIdx.x, tid = threadIdx.x;
    int w = tid >> 6, lane = tid & 63;
    int l15 = lane & 15, lq = lane >> 4;
    float* zb = z + (size_t)b * (SS * FF);
    float* accb = acc + (size_t)b * (SS * FF);

    // ---- phase 0: x0 = z + 0.1*delta; deferred acc; split to LDS
    float wa = wact[b];
    f32x4 dv = *(const f32x4*)(delta + b * FF + lane * 4);
    bool doacc = (wa != 0.0f);
#pragma unroll
    for (int it = 0; it < 8; ++it) {
        int i = w * 8 + it;
        f32x4 zv = *(const f32x4*)(zb + (size_t)i * FF + lane * 4);
        f32x4 x0;
#pragma unroll
        for (int jj = 0; jj < 4; ++jj) x0[jj] = zv[jj] + 0.1f * dv[jj];
        if (doacc) {
            f32x4 av = *(const f32x4*)(accb + (size_t)i * FF + lane * 4);
#pragma unroll
            for (int jj = 0; jj < 4; ++jj) av[jj] += wa * x0[jj];
            *(f32x4*)(accb + (size_t)i * FF + lane * 4) = av;
        }
        half4 h4, l4;
#pragma unroll
        for (int jj = 0; jj < 4; ++jj) {
            half_t h = (half_t)x0[jj];
            h4[jj] = h; l4[jj] = (half_t)(x0[jj] - (float)h);
        }
        *(half4*)&Zh[i * 264 + lane * 4] = h4;
        *(half4*)&Zl[i * 264 + lane * 4] = l4;
    }
    __syncthreads();   // sync 1: Z staged

    // ---- phase T: T = x0 @ G, wave w owns 32-col band.
    {
        f32x4 tac[4][2];
#pragma unroll
        for (int mt = 0; mt < 4; ++mt)
#pragma unroll
            for (int nt = 0; nt < 2; ++nt) tac[mt][nt] = (f32x4){0.f, 0.f, 0.f, 0.f};
        for (int kt = 0; kt < 8; ++kt) {
            int kc = kt * 32 + lq * 8;
            half8 ah[4], al[4], gh[2], gl[2];
#pragma unroll
            for (int mt = 0; mt < 4; ++mt) {
                int ro = (mt * 16 + l15) * 264 + kc;
                ah[mt] = *(const half8*)&Zh[ro];
                al[mt] = *(const half8*)&Zl[ro];
            }
#pragma unroll
            for (int nt = 0; nt < 2; ++nt) {
                size_t go = (size_t)(w * 32 + nt * 16 + l15) * 256 + kc;
                gh[nt] = *(const half8*)(GTh + go);
                gl[nt] = *(const half8*)(GTl + go);
            }
#pragma unroll
            for (int mt = 0; mt < 4; ++mt)
#pragma unroll
                for (int nt = 0; nt < 2; ++nt) {
                    tac[mt][nt] = __builtin_amdgcn_mfma_f32_16x16x32_f16(ah[mt], gh[nt], tac[mt][nt], 0, 0, 0);
                    tac[mt][nt] = __builtin_amdgcn_mfma_f32_16x16x32_f16(ah[mt], gl[nt], tac[mt][nt], 0, 0, 0);
                    tac[mt][nt] = __builtin_amdgcn_mfma_f32_16x16x32_f16(al[mt], gh[nt], tac[mt][nt], 0, 0, 0);
                }
        }
        const float scale = 0.08838834764831845f;   // 128^-0.5 folded into T
#pragma unroll
        for (int mt = 0; mt < 4; ++mt)
#pragma unroll
            for (int nt = 0; nt < 2; ++nt)
#pragma unroll
                for (int r = 0; r < 4; ++r) {
                    int m = mt * 16 + lq * 4 + r;
                    int n = w * 32 + nt * 16 + l15;
                    float v = tac[mt][nt][r] * scale;
                    half_t h = (half_t)v;
                    Ubuf[0][m * 264 + n] = h;
                    Ubuf[1][m * 264 + n] = (half_t)(v - (float)h);
                }
    }
    __syncthreads();   // sync 2: T ready

    // ---- phase B: waves 0-3: S/softmax/P; all waves: V band.
    if (w < 4) {
        f32x4 sac[4];
#pragma unroll
        for (int jt = 0; jt < 4; ++jt) sac[jt] = (f32x4){0.f, 0.f, 0.f, 0.f};
        for (int kt = 0; kt < 8; ++kt) {
            int kc = kt * 32 + lq * 8;
            int to = (w * 16 + l15) * 264 + kc;
            half8 bh = *(const half8*)&Ubuf[0][to];
            half8 bl = *(const half8*)&Ubuf[1][to];
            half8 ah[4], al[4];
#pragma unroll
            for (int jt = 0; jt < 4; ++jt) {
                int ro = (jt * 16 + l15) * 264 + kc;
                ah[jt] = *(const half8*)&Zh[ro];
                al[jt] = *(const half8*)&Zl[ro];
            }
#pragma unroll
            for (int jt = 0; jt < 4; ++jt) {
                sac[jt] = __builtin_amdgcn_mfma_f32_16x16x32_f16(ah[jt], bh, sac[jt], 0, 0, 0);
                sac[jt] = __builtin_amdgcn_mfma_f32_16x16x32_f16(ah[jt], bl, sac[jt], 0, 0, 0);
                sac[jt] = __builtin_amdgcn_mfma_f32_16x16x32_f16(al[jt], bh, sac[jt], 0, 0, 0);
            }
        }
        float sv[4][4];
        float mx = -1e30f;
#pragma unroll
        for (int jt = 0; jt < 4; ++jt)
#pragma unroll
            for (int r = 0; r < 4; ++r) { sv[jt][r] = sac[jt][r]; mx = fmaxf(mx, sv[jt][r]); }
        mx = fmaxf(mx, __shfl_xor(mx, 16));
        mx = fmaxf(mx, __shfl_xor(mx, 32));
        float ssum = 0.f;
#pragma unroll
        for (int jt = 0; jt < 4; ++jt)
#pragma unroll
            for (int r = 0; r < 4; ++r) { float e = expf(sv[jt][r] - mx); sv[jt][r] = e; ssum += e; }
        ssum += __shfl_xor(ssum, 16);
        ssum += __shfl_xor(ssum, 32);
        float inv = 1.f / ssum;
#pragma unroll
        for (int jt = 0; jt < 4; ++jt) {
            half4 h4, l4;
#pragma unroll
            for (int r = 0; r < 4; ++r) {
                float pv = sv[jt][r] * inv;
                half_t hh = (half_t)pv;
                h4[r] = hh;
                l4[r] = (half_t)(pv - (float)hh);
            }
            *(half4*)&Pbuf[0][w][l15 * 72 + jt * 16 + lq * 4] = h4;
            *(half4*)&Pbuf[1][w][l15 * 72 + jt * 16 + lq * 4] = l4;
        }
    }

    f32x4 vac[4][2];
#pragma unroll
    for (int mt = 0; mt < 4; ++mt)
#pragma unroll
        for (int nt = 0; nt < 2; ++nt) vac[mt][nt] = (f32x4){0.f, 0.f, 0.f, 0.f};
    for (int kt = 0; kt < 8; ++kt) {
        int kc = kt * 32 + lq * 8;
        half8 ah[4], al[4], gh[2], gl[2];
#pragma unroll
        for (int mt = 0; mt < 4; ++mt) {
            int ro = (mt * 16 + l15) * 264 + kc;
            ah[mt] = *(const half8*)&Zh[ro];
            al[mt] = *(const half8*)&Zl[ro];
        }
#pragma unroll
        for (int nt = 0; nt < 2; ++nt) {
            size_t go = (size_t)(w * 32 + nt * 16 + l15) * 256 + kc;
            gh[nt] = *(const half8*)(WvTh + go);
            gl[nt] = *(const half8*)(WvTl + go);
        }
#pragma unroll
        for (int mt = 0; mt < 4; ++mt)
#pragma unroll
            for (int nt = 0; nt < 2; ++nt) {
                vac[mt][nt] = __builtin_amdgcn_mfma_f32_16x16x32_f16(ah[mt], gh[nt], vac[mt][nt], 0, 0, 0);
                vac[mt][nt] = __builtin_amdgcn_mfma_f32_16x16x32_f16(ah[mt], gl[nt], vac[mt][nt], 0, 0, 0);
                vac[mt][nt] = __builtin_amdgcn_mfma_f32_16x16x32_f16(al[mt], gh[nt], vac[mt][nt], 0, 0, 0);
            }
    }
    __syncthreads();   // sync 3

    // VT write
#pragma unroll
    for (int mt = 0; mt < 4; ++mt)
#pragma unroll
        for (int nt = 0; nt < 2; ++nt) {
            int n = w * 32 + nt * 16 + l15;
            int m0 = mt * 16 + lq * 4;
            half4 h4, l4;
#pragma unroll
            for (int r = 0; r < 4; ++r) {
                float v = vac[mt][nt][r];
                half_t h = (half_t)v;
                h4[r] = h; l4[r] = (half_t)(v - (float)h);
            }
            *(half4*)&Ubuf[0][n * 72 + m0] = h4;
            *(half4*)&Ubuf[1][n * 72 + m0] = l4;
        }
    __syncthreads();   // sync 4

    // ---- phase O
    f32x4 oc[4][2];
#pragma unroll
    for (int mt = 0; mt < 4; ++mt)
#pragma unroll
        for (int nt = 0; nt < 2; ++nt) oc[mt][nt] = (f32x4){0.f, 0.f, 0.f, 0.f};
#pragma unroll
    for (int kt = 0; kt < 2; ++kt) {
        half8 pah[4], pal[4];
#pragma unroll
        for (int mt = 0; mt < 4; ++mt) {
            int po = l15 * 72 + kt * 32 + lq * 8;
            pah[mt] = *(const half8*)&Pbuf[0][mt][po];
            pal[mt] = *(const half8*)&Pbuf[1][mt][po];
        }
#pragma unroll
        for (int nt = 0; nt < 2; ++nt) {
            int n = w * 32 + nt * 16 + l15;
            half8 vbh = *(const half8*)&Ubuf[0][n * 72 + kt * 32 + lq * 8];
            half8 vbl = *(const half8*)&Ubuf[1][n * 72 + kt * 32 + lq * 8];
#pragma unroll
            for (int mt = 0; mt < 4; ++mt) {
                oc[mt][nt] = __builtin_amdgcn_mfma_f32_16x16x32_f16(pah[mt], vbh, oc[mt][nt], 0, 0, 0);
                oc[mt][nt] = __builtin_amdgcn_mfma_f32_16x16x32_f16(pah[mt], vbl, oc[mt][nt], 0, 0, 0);
                oc[mt][nt] = __builtin_amdgcn_mfma_f32_16x16x32_f16(pal[mt], vbh, oc[mt][nt], 0, 0, 0);
            }
        }
    }

    // ---- epilogue
    float zfs[2] = {0.f, 0.f};
#pragma unroll
    for (int mt = 0; mt < 4; ++mt)
#pragma unroll
        for (int nt = 0; nt < 2; ++nt)
#pragma unroll
            for (int r = 0; r < 4; ++r) {
                int i = mt * 16 + lq * 4 + r;
                int c = w * 32 + nt * 16 + l15;
                int zo = i * 264 + c;
                float x0 = (float)Zh[zo] + (float)Zl[zo];
                float z1 = oc[mt][nt][r] + 0.1f * x0;
                zb[(size_t)i * FF + c] = z1;
                zfs[nt] += z1;
            }
#pragma unroll
    for (int nt = 0; nt < 2; ++nt) {
        zfs[nt] += __shfl_xor(zfs[nt], 16);
        zfs[nt] += __shfl_xor(zfs[nt], 32);
    }
    if (lq == 0) {
#pragma unroll
        for (int nt = 0; nt < 2; ++nt)
            zf1[b * FF + w * 32 + nt * 16 + l15] = zfs[nt] * (1.f / 64.f);
    }
}

// ---------------------------------------------------------------------------
// Fused stack path: gate -> ptr -> mem update -> memqkv (split MFMA into LDS)
// -> memattn -> read -> mag z-sweep -> zf2/pval.  One block (4 waves)/batch.
__global__ __launch_bounds__(256, 2) void k_stack(
        const float* __restrict__ zf1,
        const float* __restrict__ ctrl_w, const float* __restrict__ ctrl_b,
        float* __restrict__ ptrv, float* __restrict__ memv,
        const half_t* __restrict__ MTh, const half_t* __restrict__ MTl,
        const float* __restrict__ z,
        float* __restrict__ readv, float* __restrict__ zf2,
        const float* __restrict__ halt_w, const float* __restrict__ halt_b,
        float* __restrict__ pval, float* __restrict__ magpart) {
    __shared__ float zf[256];
    __shared__ float g[3];
    __shared__ float oldp[16];
    __shared__ float np[16];
    __shared__ half_t Mh[16 * 264];
    __shared__ half_t Ml[16 * 264];
    __shared__ float Q[16][776];          // memqkv fp32, never hits global
    __shared__ float sm[16][17];
    __shared__ float rowmax[16], rowsum[16], pw[16];
    __shared__ float rd[256];
    __shared__ float red[256];

    int b = blockIdx.x, tid = threadIdx.x;
    int w = tid >> 6, lane = tid & 63;
    int l15 = lane & 15, lq = lane >> 4;

    // 1. gates from zf1
    zf[tid] = zf1[b * FF + tid];
    if (tid < 16) oldp[tid] = ptrv[b * STK + tid];
    __syncthreads();
    if (w < 3) {
        float s = 0.f;
#pragma unroll
        for (int q = 0; q < 4; ++q) {
            int c = lane + 64 * q;
            s += zf[c] * ctrl_w[c * 3 + w];
        }
#pragma unroll
        for (int off = 1; off < 64; off <<= 1) s += __shfl_xor(s, off);
        if (lane == 0) g[w] = 1.f / (1.f + expf(-(s + ctrl_b[w])));
    }
    __syncthreads();
    float tot = g[0] + g[1] + g[2] + 1e-6f;
    float push = g[0] / tot, pop = g[1] / tot, stay = g[2] / tot;
    if (tid < 16) {
        int s = tid;
        float v = push * oldp[(s + 15) & 15] + pop * oldp[(s + 1) & 15] + stay * oldp[s];
        np[s] = v;
        ptrv[b * STK + s] = v;
    }

    // 2. mem update + fp16 split into LDS
    for (int t16 = 0; t16 < 16; ++t16) {
        size_t gi = (size_t)b * (STK * FF) + t16 * 256 + tid;
        float m = memv[gi];
        float mn = m * (1.f - push) + push * zf[tid];
        memv[gi] = mn;
        half_t h = (half_t)mn;
        Mh[t16 * 264 + tid] = h;
        Ml[t16 * 264 + tid] = (half_t)(mn - (float)h);
    }
    __syncthreads();

    // 3. memqkv = memnew @ W (3-term split MFMA), wave w -> cols [w*192, w*192+192)
    {
        f32x4 qa[12];
#pragma unroll
        for (int nt = 0; nt < 12; ++nt) qa[nt] = (f32x4){0.f, 0.f, 0.f, 0.f};
        for (int kt = 0; kt < 8; ++kt) {
            int kc = kt * 32 + lq * 8;
            half8 ah = *(const half8*)&Mh[l15 * 264 + kc];
            half8 al = *(const half8*)&Ml[l15 * 264 + kc];
#pragma unroll
            for (int nt = 0; nt < 12; ++nt) {
                size_t go = (size_t)(w * 192 + nt * 16 + l15) * 256 + kc;
                half8 gh = *(const half8*)(MTh + go);
                half8 gl = *(const half8*)(MTl + go);
                qa[nt] = __builtin_amdgcn_mfma_f32_16x16x32_f16(ah, gh, qa[nt], 0, 0, 0);
                qa[nt] = __builtin_amdgcn_mfma_f32_16x16x32_f16(ah, gl, qa[nt], 0, 0, 0);
                qa[nt] = __builtin_amdgcn_mfma_f32_16x16x32_f16(al, gh, qa[nt], 0, 0, 0);
            }
        }
#pragma unroll
        for (int nt = 0; nt < 12; ++nt)
#pragma unroll
            for (int r = 0; r < 4; ++r)
                Q[lq * 4 + r][w * 192 + nt * 16 + l15] = qa[nt][r];
    }
    __syncthreads();

    // 4. memattn: scores (i=tid>>4, j=tid&15), softmax, pw = ptr^T P
    {
        int i = tid >> 4, j = tid & 15;
        float s = 0.f;
#pragma unroll 8
        for (int c = 0; c < 256; ++c) s += Q[i][c] * Q[j][256 + c];
        s *= 0.08838834764831845f;
        sm[i][j] = s;
        __syncthreads();
        if (tid < 16) {
            float m = -1e30f;
            for (int jj = 0; jj < 16; ++jj) m = fmaxf(m, sm[tid][jj]);
            float su = 0.f;
            for (int jj = 0; jj < 16; ++jj) su += expf(sm[tid][jj] - m);
            rowmax[tid] = m; rowsum[tid] = su;
        }
        __syncthreads();
        float p = expf(s - rowmax[i]) / rowsum[i];
        sm[i][j] = p;
        __syncthreads();
        if (tid < 16) {
            float a = 0.f;
            for (int ss2 = 0; ss2 < 16; ++ss2) a += np[ss2] * sm[ss2][tid];
            pw[tid] = a;
        }
        __syncthreads();
    }
    // read[c] = sum_j pw[j] * V[j][c]
    {
        float a = 0.f;
#pragma unroll
        for (int jj = 0; jj < 16; ++jj) a += pw[jj] * Q[jj][512 + tid];
        rd[tid] = a;
        readv[b * FF + tid] = a;
        float z2 = zf[tid] + 0.1f * a;     // zf2 = zf1 + 0.1*read
        zf2[b * FF + tid] = z2;
        zf[tid] = z2;                       // reuse zf for halting dot
    }
    __syncthreads();

    // 5. mag sweep over z (post-attn z1) + 0.1*read
    {
        int d = tid & 127;
        int hf = tid >> 7;
        float rr = 0.1f * rd[d];
        float ri = 0.1f * rd[DD + d];
        float ms = 0.f, msq = 0.f;
        const float* zb = z + (size_t)b * (SS * FF);
        for (int s32 = 0; s32 < 32; ++s32) {
            int s = hf * 32 + s32;
            float zr = zb[s * FF + d] + rr;
            float zi = zb[s * FF + DD + d] + ri;
            float m2 = zr * zr + zi * zi;
            ms += sqrtf(m2); msq += m2;
        }
        red[tid] = ms;
        __syncthreads();
        for (int off = 128; off > 0; off >>= 1) {
            if (tid < off) red[tid] += red[tid + off];
            __syncthreads();
        }
        float tms = red[0];
        __syncthreads();
        red[tid] = msq;
        __syncthreads();
        for (int off = 128; off > 0; off >>= 1) {
            if (tid < off) red[tid] += red[tid + off];
            __syncthreads();
        }
        float tmsq = red[0];
        __syncthreads();
        if (tid == 0) { magpart[2 * b] = tms; magpart[2 * b + 1] = tmsq; }
        // halting p from zf2
        float hp = zf[tid] * halt_w[tid];
        red[tid] = hp;
        __syncthreads();
        for (int off = 128; off > 0; off >>= 1) {
            if (tid < off) red[tid] += red[tid + off];
            __syncthreads();
        }
        if (tid == 0) pval[b] = 1.f / (1.f + expf(-(red[0] + halt_b[0])));
    }
}

// ---------------------------------------------------------------------------
__device__ __forceinline__ float bredsum(float v, float* red, int n) {
    red[n] = v; __syncthreads();
    for (int off = 64; off > 0; off >>= 1) {
        if (n < off) red[n] += red[n + off];
        __syncthreads();
    }
    float r = red[0];
    __syncthreads();
    return r;
}
__device__ __forceinline__ float bredmax(float v, float* red, int n) {
    red[n] = v; __syncthreads();
    for (int off = 64; off > 0; off >>= 1) {
        if (n < off) red[n] = fmaxf(red[n], red[n + off]);
        __syncthreads();
    }
    float r = red[0];
    __syncthreads();
    return r;
}

// VQ + ACT bookkeeping; writes delta = read + quant.
__global__ __launch_bounds__(128) void k_vq(const float* __restrict__ zf2,
                                            const float* __restrict__ cb,
                                            const float* __restrict__ cb2,
                                            const float* __restrict__ adj,
                                            float* __restrict__ probs,
                                            float* __restrict__ delta,
                                            const float* __restrict__ readv,
                                            float* __restrict__ halt,
                                            const float* __restrict__ pval,
                                            float* __restrict__ wact,
                                            const float* __restrict__ magpart, int t) {
    __shared__ float red[128];
    __shared__ float zf[256];
    __shared__ float pr[128];
    int b = blockIdx.x, n = threadIdx.x;
    zf[n] = zf2[b * FF + n];
    zf[DD + n] = zf2[b * FF + DD + n];
    float up = 0.f;
    if (t > 0) {
        float pa = 0.f, pb = 0.f;
        for (int k = n; k < BB; k += 128) { pa += magpart[2 * k]; pb += magpart[2 * k + 1]; }
        float tms = bredsum(pa, red, n);
        float tmsq = bredsum(pb, red, n);
        const float N = 4194304.f;   // B*S*D
        float mean = tms / N;
        float var = tmsq / N - mean * mean;
        float x = var / (1.f + 1e-6f);
        up = (x > 20.f) ? x : log1pf(expf(x));
    }
    __syncthreads();
    float part = zf[n] * zf[n] + zf[DD + n] * zf[DD + n];
    float zz = bredsum(part, red, n);
    float dot = 0.f;
    const float* cbn = cb + n * FF;
#pragma unroll 8
    for (int c = 0; c < FF; ++c) dot += zf[c] * cbn[c];
    float dist = (zz + cb2[n] - 2.f * dot) * (1.f / 256.f);
    float dtot = dist;
    if (t > 0) {
        float gb = 0.f;
        const float* pp = probs + b * NSYM;
        for (int k = 0; k < NSYM; ++k) gb += pp[k] * adj[k * NSYM + n];
        dtot = dist - 0.01f * up * (1.f / (1.f + expf(-gb)));
    }
    float v = -dtot;   // TEMP = 1
    float mx = bredmax(v, red, n);
    float e = expf(v - mx);
    float se = bredsum(e, red, n);
    float psm = e / se;
    pr[n] = psm;
    __syncthreads();
    probs[b * NSYM + n] = psm;
    float q0 = 0.f, q1 = 0.f;
    for (int k = 0; k < NSYM; ++k) {
        float pk = pr[k];
        q0 += pk * cb[k * FF + n];
        q1 += pk * cb[k * FF + DD + n];
    }
    delta[b * FF + n]      = readv[b * FF + n] + q0;
    delta[b * FF + DD + n] = readv[b * FF + DD + n] + q1;
    if (n == 0) {
        float h = halt[b], p = pval[b];
        float running = (h < 0.99f) ? 1.f : 0.f;
        float w = (((h + p * running) >= 0.99f) ? (1.f - h) : p) * running;
        halt[b] = h + w;
        wact[b] = w;
    }
}

// Final deferred quant/read + ACT accumulation.
__global__ __launch_bounds__(256) void k_epilogue(const float* __restrict__ z,
                                                  const float* __restrict__ delta,
                                                  const float* __restrict__ wact,
                                                  float* __restrict__ acc) {
    int idx = blockIdx.x * 256 + threadIdx.x;   // grid 32768 -> 8388608
    int b = idx >> 14;
    int c = idx & 255;
    float wa = wact[b];
    if (wa != 0.0f)
        acc[idx] += wa * (z[idx] + 0.1f * delta[b * FF + c]);
}

// ---------------------------------------------------------------------------
extern "C" void kernel_launch(void* const* d_in, const int* in_sizes, int n_in,
                              void* d_out, int out_size, void* d_ws, size_t ws_size,
                              hipStream_t stream) {
    const float* z_real  = (const float*)d_in[0];
    const float* z_imag  = (const float*)d_in[1];
    const float* attn_wr = (const float*)d_in[2];
    const float* attn_wi = (const float*)d_in[3];
    const float* mem_wr  = (const float*)d_in[4];
    const float* mem_wi  = (const float*)d_in[5];
    const float* ctrl_w  = (const float*)d_in[6];
    const float* ctrl_b  = (const float*)d_in[7];
    const float* halt_w  = (const float*)d_in[8];
    const float* halt_b  = (const float*)d_in[9];
    const float* codebook  = (const float*)d_in[10];
    const float* adjacency = (const float*)d_in[11];

    float* ws = (float*)d_ws;
    float* z      = ws + Z_OFF;
    float* WT32   = ws + QKV_OFF;
    half_t* GTh   = (half_t*)(ws + QKV_OFF + 196608);
    half_t* GTl   = GTh + 65536;
    half_t* WvTh  = GTl + 65536;
    half_t* WvTl  = WvTh + 65536;
    float* memv   = ws + MEM_OFF;
    float* ptrv   = ws + PTR_OFF;
    float* zf1    = ws + ZF1_OFF;
    float* zf2    = ws + ZF2_OFF;
    float* readv  = ws + READ_OFF;
    float* probs  = ws + PROBS_OFF;
    float* delta  = ws + DELTA_OFF;
    float* halt   = ws + HALT_OFF;
    float* pval   = ws + PVAL_OFF;
    float* wact   = ws + WACT_OFF;
    float* magp   = ws + MAGP_OFF;
    half_t* MTh   = (half_t*)(ws + MQKV_OFF);
    half_t* MTl   = (half_t*)(ws + MQKV_OFF) + 196608;
    float* cb2    = ws + CB2_OFF;
    float* acc    = (float*)d_out;

    k_buildwt32<<<768, 256, 0, stream>>>(attn_wr, attn_wi, WT32);
    k_buildG<<<256, 256, 0, stream>>>(WT32, GTh, GTl);
    k_splitWv<<<256, 256, 0, stream>>>(WT32, WvTh, WvTl);
    k_buildwt<<<768, 256, 0, stream>>>(mem_wr, mem_wi, MTh, MTl);
    k_cb2<<<1, 128, 0, stream>>>(codebook, cb2);
    k_init<<<32768, 256, 0, stream>>>(z_real, z_imag, z, memv, ptrv, probs, halt, acc,
                                      delta, wact);

    for (int t = 0; t < NDEPTH; ++t) {
        k_attn8<<<BB, 512, 0, stream>>>(z, GTh, GTl, WvTh, WvTl, delta, wact, acc, zf1);
        k_stack<<<BB, 256, 0, stream>>>(zf1, ctrl_w, ctrl_b, ptrv, memv, MTh, MTl,
                                        z, readv, zf2, halt_w, halt_b, pval, magp);
        k_vq<<<BB, 128, 0, stream>>>(zf2, codebook, cb2, adjacency, probs, delta, readv,
                                     halt, pval, wact, magp, t);
    }
    k_epilogue<<<32768, 256, 0, stream>>>(z, delta, wact, acc);
}

// Round 8
// 977.255 us; speedup vs baseline: 1.1081x; 1.1081x over previous
//
#include <hip/hip_runtime.h>
#include <math.h>

// Problem constants
#define BB 512
#define SS 64
#define DD 128
#define FF 256   // 2D
#define NSYM 128
#define STK 16
#define NDEPTH 8

typedef _Float16 half_t;
typedef __attribute__((ext_vector_type(4))) _Float16 half4;
typedef __attribute__((ext_vector_type(8))) _Float16 half8;
typedef __attribute__((ext_vector_type(4))) float f32x4;

// Workspace offsets (in floats)
#define Z_OFF      0ull                    // B*S*F      = 8388608
#define QKV_OFF    8388608ull              // WT32 + GT/WvT split planes
#define ZFW_OFF    33554432ull             // B*768      = 393216 (was memv)
#define QBUF_OFF   35651584ull             // B*16*768   = 6291456 (Q state)
#define PTR_OFF    41943040ull             // B*16       = 8192
#define ZF1_OFF    41951232ull             // B*256      = 131072
#define ZF2_OFF    42082304ull             // B*256      = 131072
#define READ_OFF   42213376ull             // B*256      = 131072
#define PROBS_OFF  42344448ull             // B*128      = 65536
#define DELTA_OFF  42409984ull             // B*256      = 131072 (read + quant)
#define HALT_OFF   42541056ull             // B          = 512
#define PVAL_OFF   42541568ull             // B          = 512
#define WACT_OFF   42542080ull             // B          = 512
#define MAGP_OFF   42542592ull             // 2048*2     = 4096
#define MQKV_OFF   42740224ull             // 196608 floats (MTh+MTl fp16)
#define CB2_OFF    42936832ull             // 128

// ---------------------------------------------------------------------------
// Combined transposed weight, fp32: WT32[h][c][e] = W_h[e][c], h in {q,k,v}
__global__ void k_buildwt32(const float* __restrict__ wr, const float* __restrict__ wi,
                            float* __restrict__ WT32) {
    int idx = blockIdx.x * 256 + threadIdx.x;   // 196608 total, grid=768
    if (idx >= 768 * 256) return;
    int col = idx >> 8;     // 0..767 = h*256 + c
    int e   = idx & 255;
    int h   = col >> 8;
    int c   = col & 255;
    const float* Wr = wr + h * DD * DD;
    const float* Wi = wi + h * DD * DD;
    float v;
    if (c < DD) {
        v = (e < DD) ? Wr[c * DD + e] : -Wi[c * DD + (e - DD)];
    } else {
        int j = c - DD;
        v = (e < DD) ? Wi[j * DD + e] : Wr[j * DD + (e - DD)];
    }
    WT32[idx] = v;
}

// GT[n][e] = G[e][n] = sum_c Wq[e][c]*Wk[n][c], split to fp16 h/l (unscaled).
__global__ __launch_bounds__(256) void k_buildG(const float* __restrict__ WT32,
                                                half_t* __restrict__ GTh,
                                                half_t* __restrict__ GTl) {
    __shared__ float kcol[256];
    int n = blockIdx.x;       // 0..255
    int e = threadIdx.x;      // 0..255
    kcol[e] = WT32[65536 + e * 256 + n];   // Wk[n][c=e]
    __syncthreads();
    float s = 0.f;
    for (int c = 0; c < 256; ++c) s += kcol[c] * WT32[c * 256 + e];  // Wq[e][c]
    half_t h = (half_t)s;
    GTh[n * 256 + e] = h;
    GTl[n * 256 + e] = (half_t)(s - (float)h);
}

__global__ void k_splitWv(const float* __restrict__ WT32,
                          half_t* __restrict__ WvTh, half_t* __restrict__ WvTl) {
    int idx = blockIdx.x * 256 + threadIdx.x;   // 65536, grid 256
    float v = WT32[131072 + idx];   // WvT[n][e] = Wv[e][n]
    half_t h = (half_t)v;
    WvTh[idx] = h;
    WvTl[idx] = (half_t)(v - (float)h);
}

// Memory-path combined transposed split weights.
__global__ void k_buildwt(const float* __restrict__ wr, const float* __restrict__ wi,
                          half_t* __restrict__ WTh, half_t* __restrict__ WTl) {
    int idx = blockIdx.x * 256 + threadIdx.x;   // 196608 total, grid=768
    if (idx >= 768 * 256) return;
    int col = idx >> 8;
    int e   = idx & 255;
    int h   = col >> 8;
    int c   = col & 255;
    const float* Wr = wr + h * DD * DD;
    const float* Wi = wi + h * DD * DD;
    float v;
    if (c < DD) {
        v = (e < DD) ? Wr[c * DD + e] : -Wi[c * DD + (e - DD)];
    } else {
        int j = c - DD;
        v = (e < DD) ? Wi[j * DD + e] : Wr[j * DD + (e - DD)];
    }
    half_t hh = (half_t)v;
    WTh[idx] = hh;
    WTl[idx] = (half_t)(v - (float)hh);
}

__global__ void k_cb2(const float* __restrict__ cb, float* __restrict__ cb2) {
    int n = threadIdx.x;   // 128 threads
    float s = 0.f;
    for (int c = 0; c < FF; ++c) { float v = cb[n * FF + c]; s += v * v; }
    cb2[n] = s;
}

__global__ __launch_bounds__(256) void k_init(const float* __restrict__ zr_in,
                                              const float* __restrict__ zi_in,
                                              float* __restrict__ z, float* __restrict__ qbuf,
                                              float* __restrict__ ptrv, float* __restrict__ probs,
                                              float* __restrict__ halt, float* __restrict__ acc,
                                              float* __restrict__ delta, float* __restrict__ wact) {
    size_t idx = (size_t)blockIdx.x * 256 + threadIdx.x;  // grid 32768 -> 8388608
    int c = (int)(idx & 255);
    size_t bs = idx >> 8;
    z[idx] = (c < DD) ? zr_in[bs * DD + c] : zi_in[bs * DD + (c - DD)];
    acc[idx] = 0.f;
    if (idx < 6291456) qbuf[idx] = 0.f;
    if (idx < 131072) delta[idx] = 0.f;
    if (idx < 8192)  ptrv[idx] = ((idx & 15) == 0) ? 1.f : 0.f;
    if (idx < 65536) probs[idx] = 0.f;
    if (idx < 512)   { halt[idx] = 0.f; wact[idx] = 0.f; }
}

// ---------------------------------------------------------------------------
// Fused attention step, 8 waves (512 thr), 1 block/CU, 2 waves/SIMD. (UNCHANGED)
__global__ __launch_bounds__(512, 1) void k_attn8(
        float* __restrict__ z,
        const half_t* __restrict__ GTh, const half_t* __restrict__ GTl,
        const half_t* __restrict__ WvTh, const half_t* __restrict__ WvTl,
        const float* __restrict__ delta, const float* __restrict__ wact,
        float* __restrict__ acc, float* __restrict__ zf1) {
    __shared__ half_t Zh[16896];         // 64 x 264 (stride-pad), 33 KB
    __shared__ half_t Zl[16896];         // 33 KB
    __shared__ half_t Ubuf[2][18432];    // union: T[64][264] / VT[256][72], 72 KB
    __shared__ half_t Pbuf[2][4][1152];  // P split, owner-wave x [16 q][72 j], 18 KB

    int b = blockIdx.x, tid = threadIdx.x;
    int w = tid >> 6, lane = tid & 63;
    int l15 = lane & 15, lq = lane >> 4;
    float* zb = z + (size_t)b * (SS * FF);
    float* accb = acc + (size_t)b * (SS * FF);

    // ---- phase 0: x0 = z + 0.1*delta; deferred acc; split to LDS
    float wa = wact[b];
    f32x4 dv = *(const f32x4*)(delta + b * FF + lane * 4);
    bool doacc = (wa != 0.0f);
#pragma unroll
    for (int it = 0; it < 8; ++it) {
        int i = w * 8 + it;
        f32x4 zv = *(const f32x4*)(zb + (size_t)i * FF + lane * 4);
        f32x4 x0;
#pragma unroll
        for (int jj = 0; jj < 4; ++jj) x0[jj] = zv[jj] + 0.1f * dv[jj];
        if (doacc) {
            f32x4 av = *(const f32x4*)(accb + (size_t)i * FF + lane * 4);
#pragma unroll
            for (int jj = 0; jj < 4; ++jj) av[jj] += wa * x0[jj];
            *(f32x4*)(accb + (size_t)i * FF + lane * 4) = av;
        }
        half4 h4, l4;
#pragma unroll
        for (int jj = 0; jj < 4; ++jj) {
            half_t h = (half_t)x0[jj];
            h4[jj] = h; l4[jj] = (half_t)(x0[jj] - (float)h);
        }
        *(half4*)&Zh[i * 264 + lane * 4] = h4;
        *(half4*)&Zl[i * 264 + lane * 4] = l4;
    }
    __syncthreads();   // sync 1: Z staged

    // ---- phase T: T = x0 @ G, wave w owns 32-col band.
    {
        f32x4 tac[4][2];
#pragma unroll
        for (int mt = 0; mt < 4; ++mt)
#pragma unroll
            for (int nt = 0; nt < 2; ++nt) tac[mt][nt] = (f32x4){0.f, 0.f, 0.f, 0.f};
        for (int kt = 0; kt < 8; ++kt) {
            int kc = kt * 32 + lq * 8;
            half8 ah[4], al[4], gh[2], gl[2];
#pragma unroll
            for (int mt = 0; mt < 4; ++mt) {
                int ro = (mt * 16 + l15) * 264 + kc;
                ah[mt] = *(const half8*)&Zh[ro];
                al[mt] = *(const half8*)&Zl[ro];
            }
#pragma unroll
            for (int nt = 0; nt < 2; ++nt) {
                size_t go = (size_t)(w * 32 + nt * 16 + l15) * 256 + kc;
                gh[nt] = *(const half8*)(GTh + go);
                gl[nt] = *(const half8*)(GTl + go);
            }
#pragma unroll
            for (int mt = 0; mt < 4; ++mt)
#pragma unroll
                for (int nt = 0; nt < 2; ++nt) {
                    tac[mt][nt] = __builtin_amdgcn_mfma_f32_16x16x32_f16(ah[mt], gh[nt], tac[mt][nt], 0, 0, 0);
                    tac[mt][nt] = __builtin_amdgcn_mfma_f32_16x16x32_f16(ah[mt], gl[nt], tac[mt][nt], 0, 0, 0);
                    tac[mt][nt] = __builtin_amdgcn_mfma_f32_16x16x32_f16(al[mt], gh[nt], tac[mt][nt], 0, 0, 0);
                }
        }
        const float scale = 0.08838834764831845f;   // 128^-0.5 folded into T
#pragma unroll
        for (int mt = 0; mt < 4; ++mt)
#pragma unroll
            for (int nt = 0; nt < 2; ++nt)
#pragma unroll
                for (int r = 0; r < 4; ++r) {
                    int m = mt * 16 + lq * 4 + r;
                    int n = w * 32 + nt * 16 + l15;
                    float v = tac[mt][nt][r] * scale;
                    half_t h = (half_t)v;
                    Ubuf[0][m * 264 + n] = h;
                    Ubuf[1][m * 264 + n] = (half_t)(v - (float)h);
                }
    }
    __syncthreads();   // sync 2: T ready

    // ---- phase B: waves 0-3: S/softmax/P; all waves: V band.
    if (w < 4) {
        f32x4 sac[4];
#pragma unroll
        for (int jt = 0; jt < 4; ++jt) sac[jt] = (f32x4){0.f, 0.f, 0.f, 0.f};
        for (int kt = 0; kt < 8; ++kt) {
            int kc = kt * 32 + lq * 8;
            int to = (w * 16 + l15) * 264 + kc;
            half8 bh = *(const half8*)&Ubuf[0][to];
            half8 bl = *(const half8*)&Ubuf[1][to];
            half8 ah[4], al[4];
#pragma unroll
            for (int jt = 0; jt < 4; ++jt) {
                int ro = (jt * 16 + l15) * 264 + kc;
                ah[jt] = *(const half8*)&Zh[ro];
                al[jt] = *(const half8*)&Zl[ro];
            }
#pragma unroll
            for (int jt = 0; jt < 4; ++jt) {
                sac[jt] = __builtin_amdgcn_mfma_f32_16x16x32_f16(ah[jt], bh, sac[jt], 0, 0, 0);
                sac[jt] = __builtin_amdgcn_mfma_f32_16x16x32_f16(ah[jt], bl, sac[jt], 0, 0, 0);
                sac[jt] = __builtin_amdgcn_mfma_f32_16x16x32_f16(al[jt], bh, sac[jt], 0, 0, 0);
            }
        }
        float sv[4][4];
        float mx = -1e30f;
#pragma unroll
        for (int jt = 0; jt < 4; ++jt)
#pragma unroll
            for (int r = 0; r < 4; ++r) { sv[jt][r] = sac[jt][r]; mx = fmaxf(mx, sv[jt][r]); }
        mx = fmaxf(mx, __shfl_xor(mx, 16));
        mx = fmaxf(mx, __shfl_xor(mx, 32));
        float ssum = 0.f;
#pragma unroll
        for (int jt = 0; jt < 4; ++jt)
#pragma unroll
            for (int r = 0; r < 4; ++r) { float e = expf(sv[jt][r] - mx); sv[jt][r] = e; ssum += e; }
        ssum += __shfl_xor(ssum, 16);
        ssum += __shfl_xor(ssum, 32);
        float inv = 1.f / ssum;
#pragma unroll
        for (int jt = 0; jt < 4; ++jt) {
            half4 h4, l4;
#pragma unroll
            for (int r = 0; r < 4; ++r) {
                float pv = sv[jt][r] * inv;
                half_t hh = (half_t)pv;
                h4[r] = hh;
                l4[r] = (half_t)(pv - (float)hh);
            }
            *(half4*)&Pbuf[0][w][l15 * 72 + jt * 16 + lq * 4] = h4;
            *(half4*)&Pbuf[1][w][l15 * 72 + jt * 16 + lq * 4] = l4;
        }
    }

    f32x4 vac[4][2];
#pragma unroll
    for (int mt = 0; mt < 4; ++mt)
#pragma unroll
        for (int nt = 0; nt < 2; ++nt) vac[mt][nt] = (f32x4){0.f, 0.f, 0.f, 0.f};
    for (int kt = 0; kt < 8; ++kt) {
        int kc = kt * 32 + lq * 8;
        half8 ah[4], al[4], gh[2], gl[2];
#pragma unroll
        for (int mt = 0; mt < 4; ++mt) {
            int ro = (mt * 16 + l15) * 264 + kc;
            ah[mt] = *(const half8*)&Zh[ro];
            al[mt] = *(const half8*)&Zl[ro];
        }
#pragma unroll
        for (int nt = 0; nt < 2; ++nt) {
            size_t go = (size_t)(w * 32 + nt * 16 + l15) * 256 + kc;
            gh[nt] = *(const half8*)(WvTh + go);
            gl[nt] = *(const half8*)(WvTl + go);
        }
#pragma unroll
        for (int mt = 0; mt < 4; ++mt)
#pragma unroll
            for (int nt = 0; nt < 2; ++nt) {
                vac[mt][nt] = __builtin_amdgcn_mfma_f32_16x16x32_f16(ah[mt], gh[nt], vac[mt][nt], 0, 0, 0);
                vac[mt][nt] = __builtin_amdgcn_mfma_f32_16x16x32_f16(ah[mt], gl[nt], vac[mt][nt], 0, 0, 0);
                vac[mt][nt] = __builtin_amdgcn_mfma_f32_16x16x32_f16(al[mt], gh[nt], vac[mt][nt], 0, 0, 0);
            }
    }
    __syncthreads();   // sync 3

    // VT write
#pragma unroll
    for (int mt = 0; mt < 4; ++mt)
#pragma unroll
        for (int nt = 0; nt < 2; ++nt) {
            int n = w * 32 + nt * 16 + l15;
            int m0 = mt * 16 + lq * 4;
            half4 h4, l4;
#pragma unroll
            for (int r = 0; r < 4; ++r) {
                float v = vac[mt][nt][r];
                half_t h = (half_t)v;
                h4[r] = h; l4[r] = (half_t)(v - (float)h);
            }
            *(half4*)&Ubuf[0][n * 72 + m0] = h4;
            *(half4*)&Ubuf[1][n * 72 + m0] = l4;
        }
    __syncthreads();   // sync 4

    // ---- phase O
    f32x4 oc[4][2];
#pragma unroll
    for (int mt = 0; mt < 4; ++mt)
#pragma unroll
        for (int nt = 0; nt < 2; ++nt) oc[mt][nt] = (f32x4){0.f, 0.f, 0.f, 0.f};
#pragma unroll
    for (int kt = 0; kt < 2; ++kt) {
        half8 pah[4], pal[4];
#pragma unroll
        for (int mt = 0; mt < 4; ++mt) {
            int po = l15 * 72 + kt * 32 + lq * 8;
            pah[mt] = *(const half8*)&Pbuf[0][mt][po];
            pal[mt] = *(const half8*)&Pbuf[1][mt][po];
        }
#pragma unroll
        for (int nt = 0; nt < 2; ++nt) {
            int n = w * 32 + nt * 16 + l15;
            half8 vbh = *(const half8*)&Ubuf[0][n * 72 + kt * 32 + lq * 8];
            half8 vbl = *(const half8*)&Ubuf[1][n * 72 + kt * 32 + lq * 8];
#pragma unroll
            for (int mt = 0; mt < 4; ++mt) {
                oc[mt][nt] = __builtin_amdgcn_mfma_f32_16x16x32_f16(pah[mt], vbh, oc[mt][nt], 0, 0, 0);
                oc[mt][nt] = __builtin_amdgcn_mfma_f32_16x16x32_f16(pah[mt], vbl, oc[mt][nt], 0, 0, 0);
                oc[mt][nt] = __builtin_amdgcn_mfma_f32_16x16x32_f16(pal[mt], vbh, oc[mt][nt], 0, 0, 0);
            }
        }
    }

    // ---- epilogue
    float zfs[2] = {0.f, 0.f};
#pragma unroll
    for (int mt = 0; mt < 4; ++mt)
#pragma unroll
        for (int nt = 0; nt < 2; ++nt)
#pragma unroll
            for (int r = 0; r < 4; ++r) {
                int i = mt * 16 + lq * 4 + r;
                int c = w * 32 + nt * 16 + l15;
                int zo = i * 264 + c;
                float x0 = (float)Zh[zo] + (float)Zl[zo];
                float z1 = oc[mt][nt][r] + 0.1f * x0;
                zb[(size_t)i * FF + c] = z1;
                zfs[nt] += z1;
            }
#pragma unroll
    for (int nt = 0; nt < 2; ++nt) {
        zfs[nt] += __shfl_xor(zfs[nt], 16);
        zfs[nt] += __shfl_xor(zfs[nt], 32);
    }
    if (lq == 0) {
#pragma unroll
        for (int nt = 0; nt < 2; ++nt)
            zf1[b * FF + w * 32 + nt * 16 + l15] = zfs[nt] * (1.f / 64.f);
    }
}

// ---------------------------------------------------------------------------
// Split-fp16 MFMA GEMM: C[M][768] = A[M][256] @ W[256][768].  Used for zfW.
__global__ __launch_bounds__(256) void gemm_split(const float* __restrict__ A,
                                                  const half_t* __restrict__ WTh,
                                                  const half_t* __restrict__ WTl,
                                                  float* __restrict__ C) {
    __shared__ float As[128][36];
    int bm = blockIdx.x / 6;
    int bn = blockIdx.x % 6;
    int tid = threadIdx.x;
    int w = tid >> 6;
    int lane = tid & 63;
    int wr = w >> 1, wc = w & 1;
    int l15 = lane & 15;
    int lq  = lane >> 4;

    f32x4 acc[4][4];
#pragma unroll
    for (int i = 0; i < 4; ++i)
#pragma unroll
        for (int j = 0; j < 4; ++j) acc[i][j] = (f32x4){0.f, 0.f, 0.f, 0.f};

    const float* Ablk = A + (size_t)bm * 128 * 256;
    int colbase = bn * 128 + wc * 64;

    int srow = tid >> 1;
    int sseg = (tid & 1) * 16;

    for (int k0 = 0; k0 < 256; k0 += 32) {
        __syncthreads();
        {
            const float* src = Ablk + (size_t)srow * 256 + k0 + sseg;
            f32x4 v0 = *(const f32x4*)(src);
            f32x4 v1 = *(const f32x4*)(src + 4);
            f32x4 v2 = *(const f32x4*)(src + 8);
            f32x4 v3 = *(const f32x4*)(src + 12);
            *(f32x4*)&As[srow][sseg]      = v0;
            *(f32x4*)&As[srow][sseg + 4]  = v1;
            *(f32x4*)&As[srow][sseg + 8]  = v2;
            *(f32x4*)&As[srow][sseg + 12] = v3;
        }
        __syncthreads();

        half8 bh[4], bl[4];
#pragma unroll
        for (int tj = 0; tj < 4; ++tj) {
            size_t off = (size_t)(colbase + tj * 16 + l15) * 256 + k0 + lq * 8;
            bh[tj] = *(const half8*)(WTh + off);
            bl[tj] = *(const half8*)(WTl + off);
        }

        half8 ah[4], al[4];
#pragma unroll
        for (int ti = 0; ti < 4; ++ti) {
            const float* ap = &As[wr * 64 + ti * 16 + l15][lq * 8];
            f32x4 a0 = *(const f32x4*)(ap);
            f32x4 a1 = *(const f32x4*)(ap + 4);
#pragma unroll
            for (int j = 0; j < 4; ++j) {
                float x = a0[j];
                half_t h = (half_t)x;
                ah[ti][j] = h;
                al[ti][j] = (half_t)(x - (float)h);
            }
#pragma unroll
            for (int j = 0; j < 4; ++j) {
                float x = a1[j];
                half_t h = (half_t)x;
                ah[ti][4 + j] = h;
                al[ti][4 + j] = (half_t)(x - (float)h);
            }
        }

#pragma unroll
        for (int ti = 0; ti < 4; ++ti)
#pragma unroll
            for (int tj = 0; tj < 4; ++tj)
                acc[ti][tj] = __builtin_amdgcn_mfma_f32_16x16x32_f16(ah[ti], bh[tj], acc[ti][tj], 0, 0, 0);
#pragma unroll
        for (int ti = 0; ti < 4; ++ti)
#pragma unroll
            for (int tj = 0; tj < 4; ++tj)
                acc[ti][tj] = __builtin_amdgcn_mfma_f32_16x16x32_f16(ah[ti], bl[tj], acc[ti][tj], 0, 0, 0);
#pragma unroll
        for (int ti = 0; ti < 4; ++ti)
#pragma unroll
            for (int tj = 0; tj < 4; ++tj)
                acc[ti][tj] = __builtin_amdgcn_mfma_f32_16x16x32_f16(al[ti], bh[tj], acc[ti][tj], 0, 0, 0);
    }

    float* Cb = C + (size_t)(bm * 128 + wr * 64) * 768 + bn * 128 + wc * 64;
#pragma unroll
    for (int ti = 0; ti < 4; ++ti)
#pragma unroll
        for (int tj = 0; tj < 4; ++tj) {
            int r0 = ti * 16 + lq * 4;
            int c0 = tj * 16 + l15;
#pragma unroll
            for (int r = 0; r < 4; ++r)
                Cb[(size_t)(r0 + r) * 768 + c0] = acc[ti][tj][r];
        }
}

// ---------------------------------------------------------------------------
// Stack step with Q-state recurrence: gate -> ptr -> Q = (1-push)Q + push*zfW
// -> memattn(Q) -> read -> zf2/pval.  One block (4 waves)/batch, 256 thr.
__global__ __launch_bounds__(256, 2) void k_stack2(
        const float* __restrict__ zf1,
        const float* __restrict__ ctrl_w, const float* __restrict__ ctrl_b,
        float* __restrict__ ptrv, float* __restrict__ qbuf,
        const float* __restrict__ zfW,
        float* __restrict__ readv, float* __restrict__ zf2,
        const float* __restrict__ halt_w, const float* __restrict__ halt_b,
        float* __restrict__ pval) {
    __shared__ float zf[256];
    __shared__ float g[3];
    __shared__ float oldp[16], np[16];
    __shared__ float Q[16][776];          // updated memqkv, LDS-resident
    __shared__ float sm[16][17];
    __shared__ float rowmax[16], rowsum[16], pw[16];
    __shared__ float red[256];

    int b = blockIdx.x, tid = threadIdx.x;
    int w = tid >> 6, lane = tid & 63;

    // 1. gates from zf1
    zf[tid] = zf1[b * FF + tid];
    if (tid < 16) oldp[tid] = ptrv[b * STK + tid];
    __syncthreads();
    if (w < 3) {
        float s = 0.f;
#pragma unroll
        for (int q = 0; q < 4; ++q) {
            int c = lane + 64 * q;
            s += zf[c] * ctrl_w[c * 3 + w];
        }
#pragma unroll
        for (int off = 1; off < 64; off <<= 1) s += __shfl_xor(s, off);
        if (lane == 0) g[w] = 1.f / (1.f + expf(-(s + ctrl_b[w])));
    }
    __syncthreads();
    float tot = g[0] + g[1] + g[2] + 1e-6f;
    float push = g[0] / tot, pop = g[1] / tot, stay = g[2] / tot;
    if (tid < 16) {
        int s = tid;
        float v = push * oldp[(s + 15) & 15] + pop * oldp[(s + 1) & 15] + stay * oldp[s];
        np[s] = v;
        ptrv[b * STK + s] = v;
    }

    // 2. Q-state update: Q_new = (1-push)*Q_old + push*zfW[b] (bcast over slots)
    float omp = 1.f - push;
    float zw0 = push * zfW[b * 768 + tid];
    float zw1 = push * zfW[b * 768 + 256 + tid];
    float zw2 = push * zfW[b * 768 + 512 + tid];
    float* qb = qbuf + (size_t)b * (STK * 768);
#pragma unroll 4
    for (int t16 = 0; t16 < 16; ++t16) {
        float q0 = qb[t16 * 768 + tid]       * omp + zw0;
        float q1 = qb[t16 * 768 + 256 + tid] * omp + zw1;
        float q2 = qb[t16 * 768 + 512 + tid] * omp + zw2;
        qb[t16 * 768 + tid]       = q0;
        qb[t16 * 768 + 256 + tid] = q1;
        qb[t16 * 768 + 512 + tid] = q2;
        Q[t16][tid] = q0;
        Q[t16][256 + tid] = q1;
        Q[t16][512 + tid] = q2;
    }
    __syncthreads();

    // 3. memattn: scores, softmax, pw = ptr^T P
    {
        int i = tid >> 4, j = tid & 15;
        float s = 0.f;
#pragma unroll 4
        for (int c = 0; c < 256; c += 4) {
            f32x4 qi = *(const f32x4*)&Q[i][c];
            f32x4 kj = *(const f32x4*)&Q[j][256 + c];
            s += qi[0] * kj[0] + qi[1] * kj[1] + qi[2] * kj[2] + qi[3] * kj[3];
        }
        s *= 0.08838834764831845f;
        sm[i][j] = s;
        __syncthreads();
        if (tid < 16) {
            float m = -1e30f;
            for (int jj = 0; jj < 16; ++jj) m = fmaxf(m, sm[tid][jj]);
            float su = 0.f;
            for (int jj = 0; jj < 16; ++jj) su += expf(sm[tid][jj] - m);
            rowmax[tid] = m; rowsum[tid] = su;
        }
        __syncthreads();
        float p = expf(s - rowmax[i]) / rowsum[i];
        sm[i][j] = p;
        __syncthreads();
        if (tid < 16) {
            float a = 0.f;
            for (int ss2 = 0; ss2 < 16; ++ss2) a += np[ss2] * sm[ss2][tid];
            pw[tid] = a;
        }
        __syncthreads();
    }

    // 4. read + zf2 + pval
    {
        float a = 0.f;
#pragma unroll
        for (int jj = 0; jj < 16; ++jj) a += pw[jj] * Q[jj][512 + tid];
        readv[b * FF + tid] = a;
        float z2 = zf[tid] + 0.1f * a;
        zf2[b * FF + tid] = z2;
        red[tid] = z2 * halt_w[tid];
        __syncthreads();
        for (int off = 128; off > 0; off >>= 1) {
            if (tid < off) red[tid] += red[tid + off];
            __syncthreads();
        }
        if (tid == 0) pval[b] = 1.f / (1.f + expf(-(red[0] + halt_b[0])));
    }
}

// ---------------------------------------------------------------------------
// Wide streaming mag sweep: 2048 blocks (4/batch), 16 rows each.
__global__ __launch_bounds__(256) void k_mag(const float* __restrict__ z,
                                             const float* __restrict__ readv,
                                             float* __restrict__ magpart) {
    __shared__ float red[256];
    int bid = blockIdx.x;
    int b = bid >> 2, q = bid & 3;
    int tid = threadIdx.x;
    int d = tid & 127, h = tid >> 7;
    float rr = 0.1f * readv[b * FF + d];
    float ri = 0.1f * readv[b * FF + DD + d];
    const float* zb = z + (size_t)b * (SS * FF);
    float ms = 0.f, msq = 0.f;
#pragma unroll
    for (int r8 = 0; r8 < 8; ++r8) {
        int s = q * 16 + h * 8 + r8;
        float zr = zb[s * FF + d] + rr;
        float zi = zb[s * FF + DD + d] + ri;
        float m2 = zr * zr + zi * zi;
        ms += sqrtf(m2); msq += m2;
    }
    red[tid] = ms;
    __syncthreads();
    for (int off = 128; off > 0; off >>= 1) {
        if (tid < off) red[tid] += red[tid + off];
        __syncthreads();
    }
    float tms = red[0];
    __syncthreads();
    red[tid] = msq;
    __syncthreads();
    for (int off = 128; off > 0; off >>= 1) {
        if (tid < off) red[tid] += red[tid + off];
        __syncthreads();
    }
    if (tid == 0) {
        magpart[bid * 2]     = tms;
        magpart[bid * 2 + 1] = red[0];
    }
}

// ---------------------------------------------------------------------------
__device__ __forceinline__ float bredsum(float v, float* red, int n) {
    red[n] = v; __syncthreads();
    for (int off = 64; off > 0; off >>= 1) {
        if (n < off) red[n] += red[n + off];
        __syncthreads();
    }
    float r = red[0];
    __syncthreads();
    return r;
}
__device__ __forceinline__ float bredmax(float v, float* red, int n) {
    red[n] = v; __syncthreads();
    for (int off = 64; off > 0; off >>= 1) {
        if (n < off) red[n] = fmaxf(red[n], red[n + off]);
        __syncthreads();
    }
    float r = red[0];
    __syncthreads();
    return r;
}

// VQ + ACT bookkeeping; writes delta = read + quant.
__global__ __launch_bounds__(128) void k_vq(const float* __restrict__ zf2,
                                            const float* __restrict__ cb,
                                            const float* __restrict__ cb2,
                                            const float* __restrict__ adj,
                                            float* __restrict__ probs,
                                            float* __restrict__ delta,
                                            const float* __restrict__ readv,
                                            float* __restrict__ halt,
                                            const float* __restrict__ pval,
                                            float* __restrict__ wact,
                                            const float* __restrict__ magpart, int t) {
    __shared__ float red[128];
    __shared__ float zf[256];
    __shared__ float pr[128];
    int b = blockIdx.x, n = threadIdx.x;
    zf[n] = zf2[b * FF + n];
    zf[DD + n] = zf2[b * FF + DD + n];
    float up = 0.f;
    if (t > 0) {
        float pa = 0.f, pb = 0.f;
        for (int k = n; k < 2048; k += 128) { pa += magpart[2 * k]; pb += magpart[2 * k + 1]; }
        float tms = bredsum(pa, red, n);
        float tmsq = bredsum(pb, red, n);
        const float N = 4194304.f;   // B*S*D
        float mean = tms / N;
        float var = tmsq / N - mean * mean;
        float x = var / (1.f + 1e-6f);
        up = (x > 20.f) ? x : log1pf(expf(x));
    }
    __syncthreads();
    float part = zf[n] * zf[n] + zf[DD + n] * zf[DD + n];
    float zz = bredsum(part, red, n);
    float dot = 0.f;
    const float* cbn = cb + n * FF;
#pragma unroll 8
    for (int c = 0; c < FF; ++c) dot += zf[c] * cbn[c];
    float dist = (zz + cb2[n] - 2.f * dot) * (1.f / 256.f);
    float dtot = dist;
    if (t > 0) {
        float gb = 0.f;
        const float* pp = probs + b * NSYM;
        for (int k = 0; k < NSYM; ++k) gb += pp[k] * adj[k * NSYM + n];
        dtot = dist - 0.01f * up * (1.f / (1.f + expf(-gb)));
    }
    float v = -dtot;   // TEMP = 1
    float mx = bredmax(v, red, n);
    float e = expf(v - mx);
    float se = bredsum(e, red, n);
    float psm = e / se;
    pr[n] = psm;
    __syncthreads();
    probs[b * NSYM + n] = psm;
    float q0 = 0.f, q1 = 0.f;
    for (int k = 0; k < NSYM; ++k) {
        float pk = pr[k];
        q0 += pk * cb[k * FF + n];
        q1 += pk * cb[k * FF + DD + n];
    }
    delta[b * FF + n]      = readv[b * FF + n] + q0;
    delta[b * FF + DD + n] = readv[b * FF + DD + n] + q1;
    if (n == 0) {
        float h = halt[b], p = pval[b];
        float running = (h < 0.99f) ? 1.f : 0.f;
        float w = (((h + p * running) >= 0.99f) ? (1.f - h) : p) * running;
        halt[b] = h + w;
        wact[b] = w;
    }
}

// Final deferred quant/read + ACT accumulation.
__global__ __launch_bounds__(256) void k_epilogue(const float* __restrict__ z,
                                                  const float* __restrict__ delta,
                                                  const float* __restrict__ wact,
                                                  float* __restrict__ acc) {
    int idx = blockIdx.x * 256 + threadIdx.x;   // grid 32768 -> 8388608
    int b = idx >> 14;
    int c = idx & 255;
    float wa = wact[b];
    if (wa != 0.0f)
        acc[idx] += wa * (z[idx] + 0.1f * delta[b * FF + c]);
}

// ---------------------------------------------------------------------------
extern "C" void kernel_launch(void* const* d_in, const int* in_sizes, int n_in,
                              void* d_out, int out_size, void* d_ws, size_t ws_size,
                              hipStream_t stream) {
    const float* z_real  = (const float*)d_in[0];
    const float* z_imag  = (const float*)d_in[1];
    const float* attn_wr = (const float*)d_in[2];
    const float* attn_wi = (const float*)d_in[3];
    const float* mem_wr  = (const float*)d_in[4];
    const float* mem_wi  = (const float*)d_in[5];
    const float* ctrl_w  = (const float*)d_in[6];
    const float* ctrl_b  = (const float*)d_in[7];
    const float* halt_w  = (const float*)d_in[8];
    const float* halt_b  = (const float*)d_in[9];
    const float* codebook  = (const float*)d_in[10];
    const float* adjacency = (const float*)d_in[11];

    float* ws = (float*)d_ws;
    float* z      = ws + Z_OFF;
    float* WT32   = ws + QKV_OFF;
    half_t* GTh   = (half_t*)(ws + QKV_OFF + 196608);
    half_t* GTl   = GTh + 65536;
    half_t* WvTh  = GTl + 65536;
    half_t* WvTl  = WvTh + 65536;
    float* zfW    = ws + ZFW_OFF;
    float* qbuf   = ws + QBUF_OFF;
    float* ptrv   = ws + PTR_OFF;
    float* zf1    = ws + ZF1_OFF;
    float* zf2    = ws + ZF2_OFF;
    float* readv  = ws + READ_OFF;
    float* probs  = ws + PROBS_OFF;
    float* delta  = ws + DELTA_OFF;
    float* halt   = ws + HALT_OFF;
    float* pval   = ws + PVAL_OFF;
    float* wact   = ws + WACT_OFF;
    float* magp   = ws + MAGP_OFF;
    half_t* MTh   = (half_t*)(ws + MQKV_OFF);
    half_t* MTl   = (half_t*)(ws + MQKV_OFF) + 196608;
    float* cb2    = ws + CB2_OFF;
    float* acc    = (float*)d_out;

    k_buildwt32<<<768, 256, 0, stream>>>(attn_wr, attn_wi, WT32);
    k_buildG<<<256, 256, 0, stream>>>(WT32, GTh, GTl);
    k_splitWv<<<256, 256, 0, stream>>>(WT32, WvTh, WvTl);
    k_buildwt<<<768, 256, 0, stream>>>(mem_wr, mem_wi, MTh, MTl);
    k_cb2<<<1, 128, 0, stream>>>(codebook, cb2);
    k_init<<<32768, 256, 0, stream>>>(z_real, z_imag, z, qbuf, ptrv, probs, halt, acc,
                                      delta, wact);

    for (int t = 0; t < NDEPTH; ++t) {
        k_attn8<<<BB, 512, 0, stream>>>(z, GTh, GTl, WvTh, WvTl, delta, wact, acc, zf1);
        gemm_split<<<(BB / 128) * 6, 256, 0, stream>>>(zf1, MTh, MTl, zfW);   // 24 blocks
        k_stack2<<<BB, 256, 0, stream>>>(zf1, ctrl_w, ctrl_b, ptrv, qbuf, zfW,
                                         readv, zf2, halt_w, halt_b, pval);
        k_mag<<<2048, 256, 0, stream>>>(z, readv, magp);
        k_vq<<<BB, 128, 0, stream>>>(zf2, codebook, cb2, adjacency, probs, delta, readv,
                                     halt, pval, wact, magp, t);
    }
    k_epilogue<<<32768, 256, 0, stream>>>(z, delta, wact, acc);
}